// Round 1
// baseline (401.335 us; speedup 1.0000x reference)
//
#include <hip/hip_runtime.h>

#define S_LEN 2048
#define NHEADS 16
#define DK 64
#define DMODEL 1024
#define QSCALE 0.18033688011f  /* 0.125 * log2(e) */

typedef float f32x4 __attribute__((ext_vector_type(4)));
typedef _Float16 f16x8 __attribute__((ext_vector_type(8)));
typedef _Float16 f16x4 __attribute__((ext_vector_type(4)));
typedef __fp16 h16x2 __attribute__((ext_vector_type(2)));   // cvt_pkrtz native type

__device__ __forceinline__ unsigned short f2h_bits(float f) {
  _Float16 h = (_Float16)f;
  unsigned short u; __builtin_memcpy(&u, &h, 2); return u;
}

__device__ __forceinline__ f32x4 mfma16(f16x8 a, f16x8 b, f32x4 c) {
  return __builtin_amdgcn_mfma_f32_16x16x32_f16(a, b, c, 0, 0, 0);
}
__device__ __forceinline__ f16x8 frag_ld(const unsigned short* p) {
  return *(const f16x8*)p;
}

#define GLD_LDS(g, l)                                                          \
  __builtin_amdgcn_global_load_lds(                                            \
      (const __attribute__((address_space(1))) void*)(g),                      \
      (__attribute__((address_space(3))) void*)(l), 16, 0, 0)

// ---------------- fp32 -> fp16 convert (contiguous) ----------------
__global__ void convert_f32_f16(const float* __restrict__ in,
                                unsigned short* __restrict__ out, int n4) {
  int i = blockIdx.x * blockDim.x + threadIdx.x;
  if (i < n4) {
    f32x4 v = *(const f32x4*)(in + (size_t)i * 4);
    unsigned short o[4];
#pragma unroll
    for (int j = 0; j < 4; j++) o[j] = f2h_bits(v[j]);
    *(uint2*)(out + (size_t)i * 4) = *(const uint2*)o;
  }
}

// ---------------- fp32 -> fp16 transpose ----------------
__global__ void transpose_f32_f16(const float* __restrict__ in,
                                  unsigned short* __restrict__ out, int R, int C) {
  __shared__ unsigned short tile[32][33];
  int bx = blockIdx.x * 32, by = blockIdx.y * 32;
  int tx = threadIdx.x, ty = threadIdx.y;
  for (int i = ty; i < 32; i += 8)
    tile[i][tx] = f2h_bits(in[(size_t)(by + i) * C + bx + tx]);
  __syncthreads();
  for (int i = ty; i < 32; i += 8)
    out[(size_t)(bx + i) * R + by + tx] = tile[tx][i];
}

// ---------------- 128x128 MFMA GEMM, B^T input (m97 structure), fp16 in fp32 acc
__launch_bounds__(256)
__global__ void gemm_bt(const unsigned short* __restrict__ A,
                        const unsigned short* __restrict__ Bt,
                        int M, int N, int K, int mode,
                        const float* __restrict__ bias,
                        float* __restrict__ out0,
                        unsigned short* __restrict__ q_o,
                        unsigned short* __restrict__ k_o,
                        unsigned short* __restrict__ v_o) {
  __shared__ __attribute__((aligned(16))) unsigned short As[128 * 32];
  __shared__ __attribute__((aligned(16))) unsigned short Bs[128 * 32];
  const int tid = threadIdx.x;
  const int w = tid >> 6, lane = tid & 63;
  const int wm = w >> 1, wn = w & 1;
  const int col = lane & 15, quad = lane >> 4;
  const int m0 = blockIdx.y * 128, n0 = blockIdx.x * 128;
  const f32x4 fzero = {0.f, 0.f, 0.f, 0.f};
  f32x4 acc[4][4];
#pragma unroll
  for (int i = 0; i < 4; i++)
#pragma unroll
    for (int j = 0; j < 4; j++) acc[i][j] = fzero;

  for (int k0 = 0; k0 < K; k0 += 32) {
    __syncthreads();
#pragma unroll
    for (int it = 0; it < 2; it++) {
      int c = it * 256 + tid;  // 512 16B-chunks per 128x32 tile
      GLD_LDS(A + (size_t)(m0 + (c >> 2)) * K + k0 + (c & 3) * 8, &As[c * 8]);
      GLD_LDS(Bt + (size_t)(n0 + (c >> 2)) * K + k0 + (c & 3) * 8, &Bs[c * 8]);
    }
    __syncthreads();
    f16x8 af[4], bfr[4];
#pragma unroll
    for (int mi = 0; mi < 4; mi++)
      af[mi] = frag_ld(&As[(wm * 64 + mi * 16 + col) * 32 + quad * 8]);
#pragma unroll
    for (int ni = 0; ni < 4; ni++)
      bfr[ni] = frag_ld(&Bs[(wn * 64 + ni * 16 + col) * 32 + quad * 8]);
#pragma unroll
    for (int mi = 0; mi < 4; mi++)
#pragma unroll
      for (int ni = 0; ni < 4; ni++)
        acc[mi][ni] = mfma16(af[mi], bfr[ni], acc[mi][ni]);
  }

#pragma unroll
  for (int mi = 0; mi < 4; mi++) {
#pragma unroll
    for (int ni = 0; ni < 4; ni++) {
      int gm_b = m0 + wm * 64 + mi * 16 + quad * 4;
      int gn = n0 + wn * 64 + ni * 16 + col;
      float bv = bias[gn];
      if (mode == 1) {
#pragma unroll
        for (int r = 0; r < 4; r++)
          out0[(size_t)(gm_b + r) * N + gn] = acc[mi][ni][r] + bv;
      } else {
        int b = gm_b >> 11, s0 = gm_b & 2047;    // M = 4*2048, s0..s0+3 same b
        int t = gn >> 10, hd = gn & 1023;        // N = 3*1024
        int h = hd >> 6, d = hd & 63;
        size_t bh = (size_t)(b * NHEADS + h);
        if (t == 2) {
          unsigned short o4[4];
#pragma unroll
          for (int r = 0; r < 4; r++) o4[r] = f2h_bits(acc[mi][ni][r] + bv);
          *(uint2*)&v_o[(bh * DK + d) * S_LEN + s0] = *(const uint2*)o4;
        } else {
          unsigned short* dst = (t == 0) ? q_o : k_o;
          float sc = (t == 0) ? QSCALE : 1.0f;
#pragma unroll
          for (int r = 0; r < 4; r++)
            dst[(bh * S_LEN + s0 + r) * DK + d] = f2h_bits((acc[mi][ni][r] + bv) * sc);
        }
      }
    }
  }
}

// ---------------- flash attention, 32-j-per-wave, LDS-free main loop ----------------
// Chunk = 128 j; each of 4 waves owns a private 32-j slice -> K/V have ZERO
// cross-wave sharing, so they are loaded straight into MFMA fragments from
// global (L2-resident), no LDS staging, no barriers in the main loop.
// PV now uses full-rate 16x16x32 (K=32 over the wave's 32 j): the QK S^T
// C-layout is EXACTLY the PV A-layout under the k-index map
//   pi(quad*8+e) = jsub*16 + quad*4 + (e&3), jsub = e>>2  (lane-local, 0 shuffles)
// and V B-frags load the same permutation as two 8B reads per ds.
// K/V frags double-buffered in registers (issue chunk n+1 before computing n).
// Max-free log2-domain softmax; bias via MFMA C-operand; cross-wave o/l
// reduction via LDS once at block end (unchanged). XCD swizzle for L2 locality.
__launch_bounds__(256, 2)
__global__ void attn_kernel(const unsigned short* __restrict__ Q,
                            const unsigned short* __restrict__ K,
                            const unsigned short* __restrict__ Vt,
                            const float* __restrict__ rel_bias,
                            unsigned short* __restrict__ ctx) {
  __shared__ __attribute__((aligned(16))) char smem[17664];
  float* brev = (float*)smem;              // 2112 f32 bias table (dead after loop)
  float* red  = (float*)smem;              // 64*68 f32 epilogue scratch (aliases brev)
  float* lred = (float*)(smem + 17408);    // 64 f32

  const int tid = threadIdx.x;
  const int w = tid >> 6, lane = tid & 63;
  const int col = lane & 15, quad = lane >> 4;
  const int bid = blockIdx.x;
  const int xcd = bid & 7, slot = bid >> 3;
  const int bh = (slot >> 5) * 8 + xcd;     // 8 bh per XCD
  const int qt = slot & 31;
  const int h = bh & (NHEADS - 1), b = bh >> 4;
  const unsigned short* qp = Q + (size_t)bh * S_LEN * DK;
  const unsigned short* kp = K + (size_t)bh * S_LEN * DK;
  const unsigned short* vp = Vt + (size_t)bh * DK * S_LEN;
  const f32x4 fzero = {0.f, 0.f, 0.f, 0.f};

  // windowed reversed bias table (log2e-scaled), idx = j - (q - qt*64) + 63
  const int tbase = 1985 - qt * 64;
#pragma unroll
  for (int it = 0; it < 9; it++) {
    int idx = it * 256 + tid;
    if (idx < 2112) {
      int rel = 3072 - (tbase + idx);
      rel = rel < 0 ? 0 : (rel > 2048 ? 2048 : rel);
      brev[idx] = rel_bias[rel * NHEADS + h] * 1.44269504089f;
    }
  }

  // Q as B-operand frags: qb[qs][ks], q = qt*64 + qs*16 + col
  f16x8 qb[4][2];
#pragma unroll
  for (int qs = 0; qs < 4; qs++)
#pragma unroll
    for (int ks = 0; ks < 2; ks++)
      qb[qs][ks] = frag_ld(qp + (size_t)(qt * 64 + qs * 16 + col) * DK + ks * 32 + quad * 8);

  f32x4 o[4][4];      // partial o[q=qs*16+quad*4+r][d=ds*16+col] over wave's j-slice
  float rsum[4];      // partial l[q=qs*16+col] over lane's j
#pragma unroll
  for (int qs = 0; qs < 4; qs++) {
#pragma unroll
    for (int ds = 0; ds < 4; ds++) o[qs][ds] = fzero;
    rsum[qs] = 0.f;
  }

  // K A-frag address: row j = w*32 + jsub*16 + col, k = ks*32 + quad*8 (16B)
  const unsigned short* kqA = kp + (size_t)(w * 32 + col) * DK + quad * 8;
  // V B-frag addresses: Vt[d = ds*16+col][w*32 + {quad*4, 16+quad*4}] (2x8B)
  const unsigned short* vq0 = vp + (size_t)(0 + col) * S_LEN + w * 32 + quad * 4;
  const unsigned short* vq1 = vp + (size_t)(16 + col) * S_LEN + w * 32 + quad * 4;
  const unsigned short* vq2 = vp + (size_t)(32 + col) * S_LEN + w * 32 + quad * 4;
  const unsigned short* vq3 = vp + (size_t)(48 + col) * S_LEN + w * 32 + quad * 4;
  // bias: idx = ck*128 + w*32 + jsub*16 + quad*4 + r - (qs*16 + col) + 63
  const float* bq = brev + (w * 32 + quad * 4 - col + 63);

  __syncthreads();  // brev ready

#define LOADK(dst)                                                             \
  dst[0][0] = frag_ld(kqA);                                                    \
  dst[0][1] = frag_ld(kqA + 32);                                               \
  dst[1][0] = frag_ld(kqA + 16 * DK);                                          \
  dst[1][1] = frag_ld(kqA + 16 * DK + 32);                                     \
  kqA += 128 * DK;

#define LOADV1(dst, i, p)                                                      \
  {                                                                            \
    f16x4 lo_ = *(const f16x4*)(p);                                            \
    f16x4 hi_ = *(const f16x4*)(p + 16);                                       \
    dst[i] = __builtin_shufflevector(lo_, hi_, 0, 1, 2, 3, 4, 5, 6, 7);        \
    p += 128;                                                                  \
  }
#define LOADV(dst)                                                             \
  LOADV1(dst, 0, vq0) LOADV1(dst, 1, vq1) LOADV1(dst, 2, vq2) LOADV1(dst, 3, vq3)

#define COMPUTE(ka, vb)                                                        \
  _Pragma("unroll")                                                            \
  for (int qs = 0; qs < 4; qs++) {                                             \
    h16x2 pk[4];                                                               \
    _Pragma("unroll")                                                          \
    for (int js = 0; js < 2; js++) {                                           \
      f32x4 bias4;                                                             \
      _Pragma("unroll")                                                        \
      for (int r = 0; r < 4; r++) bias4[r] = bq[(js - qs) * 16 + r];           \
      f32x4 sc = mfma16(ka[1][1 * 0 + 1] /*dummy*/, qb[qs][1], fzero);         \
      (void)sc;                                                                \
    }                                                                          \
  }

#undef COMPUTE
#define COMPUTE(ka, vb)                                                        \
  _Pragma("unroll")                                                            \
  for (int qs = 0; qs < 4; qs++) {                                             \
    h16x2 pk[4];                                                               \
    _Pragma("unroll")                                                          \
    for (int js = 0; js < 2; js++) {                                           \
      f32x4 bias4;                                                             \
      _Pragma("unroll")                                                        \
      for (int r = 0; r < 4; r++) bias4[r] = bq[(js - qs) * 16 + r];           \
      f32x4 sc = mfma16(ka[js][1], qb[qs][1],                                  \
                        mfma16(ka[js][0], qb[qs][0], bias4));                  \
      float p0 = __builtin_amdgcn_exp2f(sc[0]);                                \
      float p1 = __builtin_amdgcn_exp2f(sc[1]);                                \
      float p2 = __builtin_amdgcn_exp2f(sc[2]);                                \
      float p3 = __builtin_amdgcn_exp2f(sc[3]);                                \
      rsum[qs] += (p0 + p1) + (p2 + p3);                                       \
      pk[js * 2]     = __builtin_amdgcn_cvt_pkrtz(p0, p1);                     \
      pk[js * 2 + 1] = __builtin_amdgcn_cvt_pkrtz(p2, p3);                     \
    }                                                                          \
    f16x8 pa;                                                                  \
    __builtin_memcpy(&pa, pk, 16);                                             \
    _Pragma("unroll")                                                          \
    for (int ds = 0; ds < 4; ds++)                                             \
      o[qs][ds] = mfma16(pa, vb[ds], o[qs][ds]);                               \
  }

  f16x8 kaA[2][2], kaB[2][2], vbA[4], vbB[4];
  LOADK(kaA) LOADV(vbA)                      // chunk 0
  for (int ck = 0; ck < 14; ck += 2) {
    LOADK(kaB) LOADV(vbB)                    // chunk ck+1
    COMPUTE(kaA, vbA) bq += 128;
    LOADK(kaA) LOADV(vbA)                    // chunk ck+2
    COMPUTE(kaB, vbB) bq += 128;
  }
  LOADK(kaB) LOADV(vbB)                      // chunk 15
  COMPUTE(kaA, vbA) bq += 128;               // chunk 14
  COMPUTE(kaB, vbB)                          // chunk 15

  // finish l: sum over quads (j within wave) -> all lanes of col hold wave-partial l[q]
#pragma unroll
  for (int qs = 0; qs < 4; qs++) {
    rsum[qs] += __shfl_xor(rsum[qs], 16);
    rsum[qs] += __shfl_xor(rsum[qs], 32);
  }

  // cross-wave reduction (sequential, in-place; red stride 68 for alignment+banks)
  __syncthreads();
  for (int ws = 3; ws >= 0; ws--) {
    if (w == ws) {
#pragma unroll
      for (int qs = 0; qs < 4; qs++) {
#pragma unroll
        for (int ds = 0; ds < 4; ds++) {
#pragma unroll
          for (int r = 0; r < 4; r++) {
            int q = qs * 16 + quad * 4 + r, d = ds * 16 + col;
            if (ws == 3) red[q * 68 + d] = o[qs][ds][r];
            else         red[q * 68 + d] += o[qs][ds][r];
          }
        }
        int ql = qs * 16 + col;
        if (ws == 3) lred[ql] = rsum[qs];
        else         lred[ql] += rsum[qs];
      }
    }
    __syncthreads();
  }

  // cooperative readout: wave w handles q rows [w*16, w*16+16)
#pragma unroll
  for (int pass = 0; pass < 4; pass++) {
    int ql = w * 16 + pass * 4 + quad;
    f32x4 ov = *(const f32x4*)&red[ql * 68 + col * 4];
    float inv = 1.0f / lred[ql];
    h16x2 lo = __builtin_amdgcn_cvt_pkrtz(ov[0] * inv, ov[1] * inv);
    h16x2 hi = __builtin_amdgcn_cvt_pkrtz(ov[2] * inv, ov[3] * inv);
    uint2 pkd;
    __builtin_memcpy(&pkd.x, &lo, 4);
    __builtin_memcpy(&pkd.y, &hi, 4);
    *(uint2*)&ctx[((size_t)b * S_LEN + qt * 64 + ql) * DMODEL + h * DK + col * 4] = pkd;
  }
}

extern "C" void kernel_launch(void* const* d_in, const int* in_sizes, int n_in,
                              void* d_out, int out_size, void* d_ws, size_t ws_size,
                              hipStream_t stream) {
  (void)in_sizes; (void)n_in; (void)out_size; (void)ws_size;
  const float* x        = (const float*)d_in[0];
  const float* W_qkv    = (const float*)d_in[1];
  const float* b_qkv    = (const float*)d_in[2];
  const float* W_out    = (const float*)d_in[3];
  const float* b_out    = (const float*)d_in[4];
  const float* rel_bias = (const float*)d_in[5];
  float* out = (float*)d_out;

  char* ws = (char*)d_ws;
  unsigned short* xh     = (unsigned short*)(ws + 0);          // [8192,1024] f16 (aliases ctx)
  unsigned short* ctxh   = (unsigned short*)(ws + 0);
  unsigned short* Wqkv_t = (unsigned short*)(ws + 16777216);   // [3072,1024] f16
  unsigned short* Wout_t = (unsigned short*)(ws + 23068672);   // [1024,1024] f16
  unsigned short* Qb     = (unsigned short*)(ws + 25165824);   // [4,16,2048,64] f16
  unsigned short* Kb     = (unsigned short*)(ws + 41943040);   // [4,16,2048,64] f16
  unsigned short* Vtb    = (unsigned short*)(ws + 58720256);   // [4,16,64,2048] f16

  convert_f32_f16<<<(8192 * 1024 / 4 + 255) / 256, 256, 0, stream>>>(x, xh, 8192 * 1024 / 4);
  transpose_f32_f16<<<dim3(3072 / 32, 1024 / 32), dim3(32, 8), 0, stream>>>(W_qkv, Wqkv_t, 1024, 3072);
  transpose_f32_f16<<<dim3(1024 / 32, 1024 / 32), dim3(32, 8), 0, stream>>>(W_out, Wout_t, 1024, 1024);
  gemm_bt<<<dim3(3072 / 128, 8192 / 128), 256, 0, stream>>>(
      xh, Wqkv_t, 8192, 3072, 1024, 0, b_qkv, nullptr, Qb, Kb, Vtb);
  attn_kernel<<<4 * NHEADS * (S_LEN / 64), 256, 0, stream>>>(Qb, Kb, Vtb, rel_bias, ctxh);
  gemm_bt<<<dim3(1024 / 128, 8192 / 128), 256, 0, stream>>>(
      ctxh, Wout_t, 8192, 1024, 1024, 1, b_out, out, nullptr, nullptr, nullptr);
}

// Round 2
// 319.719 us; speedup vs baseline: 1.2553x; 1.2553x over previous
//
#include <hip/hip_runtime.h>

#define S_LEN 2048
#define NHEADS 16
#define DK 64
#define DMODEL 1024
#define QSCALE 0.18033688011f  /* 0.125 * log2(e) */

typedef float f32x4 __attribute__((ext_vector_type(4)));
typedef _Float16 f16x8 __attribute__((ext_vector_type(8)));
typedef _Float16 f16x4 __attribute__((ext_vector_type(4)));
typedef __fp16 h16x2 __attribute__((ext_vector_type(2)));   // cvt_pkrtz native type

__device__ __forceinline__ unsigned short f2h_bits(float f) {
  _Float16 h = (_Float16)f;
  unsigned short u; __builtin_memcpy(&u, &h, 2); return u;
}

__device__ __forceinline__ f32x4 mfma16(f16x8 a, f16x8 b, f32x4 c) {
  return __builtin_amdgcn_mfma_f32_16x16x32_f16(a, b, c, 0, 0, 0);
}
__device__ __forceinline__ f16x8 frag_ld(const unsigned short* p) {
  return *(const f16x8*)p;
}

#define GLD_LDS(g, l)                                                          \
  __builtin_amdgcn_global_load_lds(                                            \
      (const __attribute__((address_space(1))) void*)(g),                      \
      (__attribute__((address_space(3))) void*)(l), 16, 0, 0)

// ---------------- fp32 -> fp16 convert (contiguous) ----------------
__global__ void convert_f32_f16(const float* __restrict__ in,
                                unsigned short* __restrict__ out, int n4) {
  int i = blockIdx.x * blockDim.x + threadIdx.x;
  if (i < n4) {
    f32x4 v = *(const f32x4*)(in + (size_t)i * 4);
    unsigned short o[4];
#pragma unroll
    for (int j = 0; j < 4; j++) o[j] = f2h_bits(v[j]);
    *(uint2*)(out + (size_t)i * 4) = *(const uint2*)o;
  }
}

// ---------------- fp32 -> fp16 transpose ----------------
__global__ void transpose_f32_f16(const float* __restrict__ in,
                                  unsigned short* __restrict__ out, int R, int C) {
  __shared__ unsigned short tile[32][33];
  int bx = blockIdx.x * 32, by = blockIdx.y * 32;
  int tx = threadIdx.x, ty = threadIdx.y;
  for (int i = ty; i < 32; i += 8)
    tile[i][tx] = f2h_bits(in[(size_t)(by + i) * C + bx + tx]);
  __syncthreads();
  for (int i = ty; i < 32; i += 8)
    out[(size_t)(bx + i) * R + by + tx] = tile[tx][i];
}

// ---------------- 128x128 MFMA GEMM, B^T input (m97 structure), fp16 in fp32 acc
// V epilogue writes the within-32-block j-permutation pos = 32sb+8g+4jsub+r
// (from j = 32sb+16jsub+4g+r) so attn's PV B-frags are contiguous 16B reads.
__launch_bounds__(256)
__global__ void gemm_bt(const unsigned short* __restrict__ A,
                        const unsigned short* __restrict__ Bt,
                        int M, int N, int K, int mode,
                        const float* __restrict__ bias,
                        float* __restrict__ out0,
                        unsigned short* __restrict__ q_o,
                        unsigned short* __restrict__ k_o,
                        unsigned short* __restrict__ v_o) {
  __shared__ __attribute__((aligned(16))) unsigned short As[128 * 32];
  __shared__ __attribute__((aligned(16))) unsigned short Bs[128 * 32];
  const int tid = threadIdx.x;
  const int w = tid >> 6, lane = tid & 63;
  const int wm = w >> 1, wn = w & 1;
  const int col = lane & 15, quad = lane >> 4;
  const int m0 = blockIdx.y * 128, n0 = blockIdx.x * 128;
  const f32x4 fzero = {0.f, 0.f, 0.f, 0.f};
  f32x4 acc[4][4];
#pragma unroll
  for (int i = 0; i < 4; i++)
#pragma unroll
    for (int j = 0; j < 4; j++) acc[i][j] = fzero;

  for (int k0 = 0; k0 < K; k0 += 32) {
    __syncthreads();
#pragma unroll
    for (int it = 0; it < 2; it++) {
      int c = it * 256 + tid;  // 512 16B-chunks per 128x32 tile
      GLD_LDS(A + (size_t)(m0 + (c >> 2)) * K + k0 + (c & 3) * 8, &As[c * 8]);
      GLD_LDS(Bt + (size_t)(n0 + (c >> 2)) * K + k0 + (c & 3) * 8, &Bs[c * 8]);
    }
    __syncthreads();
    f16x8 af[4], bfr[4];
#pragma unroll
    for (int mi = 0; mi < 4; mi++)
      af[mi] = frag_ld(&As[(wm * 64 + mi * 16 + col) * 32 + quad * 8]);
#pragma unroll
    for (int ni = 0; ni < 4; ni++)
      bfr[ni] = frag_ld(&Bs[(wn * 64 + ni * 16 + col) * 32 + quad * 8]);
#pragma unroll
    for (int mi = 0; mi < 4; mi++)
#pragma unroll
      for (int ni = 0; ni < 4; ni++)
        acc[mi][ni] = mfma16(af[mi], bfr[ni], acc[mi][ni]);
  }

#pragma unroll
  for (int mi = 0; mi < 4; mi++) {
#pragma unroll
    for (int ni = 0; ni < 4; ni++) {
      int gm_b = m0 + wm * 64 + mi * 16 + quad * 4;
      int gn = n0 + wn * 64 + ni * 16 + col;
      float bv = bias[gn];
      if (mode == 1) {
#pragma unroll
        for (int r = 0; r < 4; r++)
          out0[(size_t)(gm_b + r) * N + gn] = acc[mi][ni][r] + bv;
      } else {
        int b = gm_b >> 11, s0 = gm_b & 2047;    // M = 4*2048, s0..s0+3 same b
        int t = gn >> 10, hd = gn & 1023;        // N = 3*1024
        int h = hd >> 6, d = hd & 63;
        size_t bh = (size_t)(b * NHEADS + h);
        if (t == 2) {
          // permuted V store: s0 = 32sb+16jsub+4g -> pos0 = 32sb+8g+4jsub
          int pos0 = (s0 & ~31) | ((s0 & 12) << 1) | ((s0 & 16) >> 2);
          unsigned short o4[4];
#pragma unroll
          for (int r = 0; r < 4; r++) o4[r] = f2h_bits(acc[mi][ni][r] + bv);
          *(uint2*)&v_o[(bh * DK + d) * S_LEN + pos0] = *(const uint2*)o4;
        } else {
          unsigned short* dst = (t == 0) ? q_o : k_o;
          float sc = (t == 0) ? QSCALE : 1.0f;
#pragma unroll
          for (int r = 0; r < 4; r++)
            dst[(bh * S_LEN + s0 + r) * DK + d] = f2h_bits((acc[mi][ni][r] + bv) * sc);
        }
      }
    }
  }
}

// ---------------- flash attention: 32-j-per-wave, LDS-staged, full-rate PV ----
// Chunk = 128 j; 4 waves each own a private 32-j slice. K (128x64 f16) and
// permuted-V (64 d-rows x 128 pos f16) staged to LDS via coalesced
// global_load_lds with XOR group-swizzle (pre-swizzled global source, swizzled
// LDS read -> conflict-free ds_read_b128 for every fragment).
// QK S^T C-layout is exactly the PV A-layout under the lane-local k-map
//   pi(quad*8+e) = (e>>2)*16 + quad*4 + (e&3)
// and the permuted V storage makes the matching B-frag one contiguous 16B read.
// PV runs full-rate 16x16x32 (was the 50%-rate K=16 limiter in the 125us ver).
// Max-free log2-domain softmax; bias via MFMA C-operand; cross-wave o/l
// reduction via LDS once at block end. XCD swizzle for K/V L2 locality.
__launch_bounds__(256, 3)
__global__ void attn_kernel(const unsigned short* __restrict__ Q,
                            const unsigned short* __restrict__ K,
                            const unsigned short* __restrict__ Vt,
                            const float* __restrict__ rel_bias,
                            unsigned short* __restrict__ ctx) {
  __shared__ __attribute__((aligned(16))) char smem[41472];
  unsigned short* Ks = (unsigned short*)smem;              // 16 KB: [128 j][64 k] swz
  unsigned short* Vs = (unsigned short*)(smem + 16384);    // 16 KB: [64 d][128 pos] swz
  float* brev = (float*)(smem + 32768);                    // 2112 f32 bias table
  float* lred = (float*)(smem + 41216);                    // 64 f32
  float* red  = (float*)smem;                              // epilogue alias (17408 B)

  const int tid = threadIdx.x;
  const int w = tid >> 6, lane = tid & 63;
  const int col = lane & 15, quad = lane >> 4;
  const int c7 = col & 7;
  const int bid = blockIdx.x;
  const int xcd = bid & 7, slot = bid >> 3;
  const int bh = (slot >> 5) * 8 + xcd;     // 8 bh per XCD
  const int qt = slot & 31;
  const int h = bh & (NHEADS - 1), b = bh >> 4;
  const unsigned short* qp = Q + (size_t)bh * S_LEN * DK;
  const unsigned short* kp = K + (size_t)bh * S_LEN * DK;
  const unsigned short* vp = Vt + (size_t)bh * DK * S_LEN;
  const f32x4 fzero = {0.f, 0.f, 0.f, 0.f};

  // windowed reversed bias table (log2e-scaled), idx = j - (q - qt*64) + 63
  const int tbase = 1985 - qt * 64;
#pragma unroll
  for (int it = 0; it < 9; it++) {
    int idx = it * 256 + tid;
    if (idx < 2112) {
      int rel = 3072 - (tbase + idx);
      rel = rel < 0 ? 0 : (rel > 2048 ? 2048 : rel);
      brev[idx] = rel_bias[rel * NHEADS + h] * 1.44269504089f;
    }
  }

  // Q as B-operand frags: qb[qs][ks], q = qt*64 + qs*16 + col
  f16x8 qb[4][2];
#pragma unroll
  for (int qs = 0; qs < 4; qs++)
#pragma unroll
    for (int ks = 0; ks < 2; ks++)
      qb[qs][ks] = frag_ld(qp + (size_t)(qt * 64 + qs * 16 + col) * DK + ks * 32 + quad * 8);

  f32x4 o[4][4];      // partial o[q=qs*16+quad*4+r][d=ds*16+col] over wave's 32 j
  float rsum[4];      // partial l[q=qs*16+col] over lane's j
#pragma unroll
  for (int qs = 0; qs < 4; qs++) {
#pragma unroll
    for (int ds = 0; ds < 4; ds++) o[qs][ds] = fzero;
    rsum[qs] = 0.f;
  }

  // ---- LDS read offsets (per-lane constants, elements) ----
  // K A-frag: row j = w*32 + jsub*16 + col, 16B slot = (ks*4+quad) ^ (row&7)
  int kaoff[2][2];
#pragma unroll
  for (int jsub = 0; jsub < 2; jsub++)
#pragma unroll
    for (int ks = 0; ks < 2; ks++)
      kaoff[jsub][ks] = (w * 32 + jsub * 16 + col) * 64 + (((ks * 4 + quad) ^ c7) * 8);
  // V B-frag: row d = ds*16+col, slot g = w*4+quad (16 slots), swz low 3 bits
  const int vg = w * 4 + quad;
  const int vboff = col * 128 + (((vg & 8) | ((vg & 7) ^ c7)) * 8);  // + ds*2048

  // ---- staging addresses (it advances rows by 32 (K) / 16 (V); group swizzle
  // is it-invariant since it shifts rows by multiples of 8) ----
  const int rK = tid >> 3, gK = (tid & 7) ^ (rK & 7);
  const int dV = tid >> 4, gsV = tid & 15;
  const int gV = (gsV & 8) | ((gsV & 7) ^ (dV & 7));
  const unsigned short* ks0 = kp + rK * DK + gK * 8;
  const unsigned short* vs0 = vp + (size_t)dV * S_LEN + gV * 8;
  unsigned short* kd0 = &Ks[tid * 8];
  unsigned short* vd0 = &Vs[tid * 8];

  // bias: idx = ck*128 + w*32 + jsub*16 + quad*4 + r - (qs*16 + col) + 63
  const float* bq = brev + (w * 32 + quad * 4 - col + 63);

#define COMPUTE(ka, vb)                                                        \
  _Pragma("unroll")                                                            \
  for (int qs = 0; qs < 4; qs++) {                                             \
    h16x2 pk[4];                                                               \
    _Pragma("unroll")                                                          \
    for (int js = 0; js < 2; js++) {                                           \
      f32x4 bias4;                                                             \
      _Pragma("unroll")                                                        \
      for (int r = 0; r < 4; r++) bias4[r] = bq[(js - qs) * 16 + r];           \
      f32x4 sc = mfma16(ka[js][1], qb[qs][1],                                  \
                        mfma16(ka[js][0], qb[qs][0], bias4));                  \
      float p0 = __builtin_amdgcn_exp2f(sc[0]);                                \
      float p1 = __builtin_amdgcn_exp2f(sc[1]);                                \
      float p2 = __builtin_amdgcn_exp2f(sc[2]);                                \
      float p3 = __builtin_amdgcn_exp2f(sc[3]);                                \
      rsum[qs] += (p0 + p1) + (p2 + p3);                                       \
      pk[js * 2]     = __builtin_amdgcn_cvt_pkrtz(p0, p1);                     \
      pk[js * 2 + 1] = __builtin_amdgcn_cvt_pkrtz(p2, p3);                     \
    }                                                                          \
    f16x8 pa;                                                                  \
    __builtin_memcpy(&pa, pk, 16);                                             \
    _Pragma("unroll")                                                          \
    for (int ds = 0; ds < 4; ds++)                                             \
      o[qs][ds] = mfma16(pa, vb[ds], o[qs][ds]);                               \
  }

  for (int ck = 0; ck < S_LEN / 128; ck++) {
    __syncthreads();  // prior-iter LDS reads done (and brev ready at ck=0)
#pragma unroll
    for (int it = 0; it < 4; it++) {
      GLD_LDS(ks0 + it * 32 * DK, kd0 + it * 2048);
      GLD_LDS(vs0 + (size_t)it * 16 * S_LEN, vd0 + it * 2048);
    }
    __syncthreads();
    f16x8 ka[2][2];
#pragma unroll
    for (int jsub = 0; jsub < 2; jsub++)
#pragma unroll
      for (int ks = 0; ks < 2; ks++)
        ka[jsub][ks] = frag_ld(&Ks[kaoff[jsub][ks]]);
    f16x8 vb[4];
#pragma unroll
    for (int ds = 0; ds < 4; ds++)
      vb[ds] = frag_ld(&Vs[vboff + ds * 2048]);
    COMPUTE(ka, vb)
    ks0 += 128 * DK; vs0 += 128; bq += 128;
  }

  // finish l: sum over quads (j within wave) -> all lanes of col hold wave-partial l[q]
#pragma unroll
  for (int qs = 0; qs < 4; qs++) {
    rsum[qs] += __shfl_xor(rsum[qs], 16);
    rsum[qs] += __shfl_xor(rsum[qs], 32);
  }

  // cross-wave reduction (sequential, in-place; red stride 68 for alignment+banks)
  __syncthreads();
  for (int ws = 3; ws >= 0; ws--) {
    if (w == ws) {
#pragma unroll
      for (int qs = 0; qs < 4; qs++) {
#pragma unroll
        for (int ds = 0; ds < 4; ds++) {
#pragma unroll
          for (int r = 0; r < 4; r++) {
            int q = qs * 16 + quad * 4 + r, d = ds * 16 + col;
            if (ws == 3) red[q * 68 + d] = o[qs][ds][r];
            else         red[q * 68 + d] += o[qs][ds][r];
          }
        }
        int ql = qs * 16 + col;
        if (ws == 3) lred[ql] = rsum[qs];
        else         lred[ql] += rsum[qs];
      }
    }
    __syncthreads();
  }

  // cooperative readout: wave w handles q rows [w*16, w*16+16)
#pragma unroll
  for (int pass = 0; pass < 4; pass++) {
    int ql = w * 16 + pass * 4 + quad;
    f32x4 ov = *(const f32x4*)&red[ql * 68 + col * 4];
    float inv = 1.0f / lred[ql];
    h16x2 lo = __builtin_amdgcn_cvt_pkrtz(ov[0] * inv, ov[1] * inv);
    h16x2 hi = __builtin_amdgcn_cvt_pkrtz(ov[2] * inv, ov[3] * inv);
    uint2 pkd;
    __builtin_memcpy(&pkd.x, &lo, 4);
    __builtin_memcpy(&pkd.y, &hi, 4);
    *(uint2*)&ctx[((size_t)b * S_LEN + qt * 64 + ql) * DMODEL + h * DK + col * 4] = pkd;
  }
}

extern "C" void kernel_launch(void* const* d_in, const int* in_sizes, int n_in,
                              void* d_out, int out_size, void* d_ws, size_t ws_size,
                              hipStream_t stream) {
  (void)in_sizes; (void)n_in; (void)out_size; (void)ws_size;
  const float* x        = (const float*)d_in[0];
  const float* W_qkv    = (const float*)d_in[1];
  const float* b_qkv    = (const float*)d_in[2];
  const float* W_out    = (const float*)d_in[3];
  const float* b_out    = (const float*)d_in[4];
  const float* rel_bias = (const float*)d_in[5];
  float* out = (float*)d_out;

  char* ws = (char*)d_ws;
  unsigned short* xh     = (unsigned short*)(ws + 0);          // [8192,1024] f16 (aliases ctx)
  unsigned short* ctxh   = (unsigned short*)(ws + 0);
  unsigned short* Wqkv_t = (unsigned short*)(ws + 16777216);   // [3072,1024] f16
  unsigned short* Wout_t = (unsigned short*)(ws + 23068672);   // [1024,1024] f16
  unsigned short* Qb     = (unsigned short*)(ws + 25165824);   // [4,16,2048,64] f16
  unsigned short* Kb     = (unsigned short*)(ws + 41943040);   // [4,16,2048,64] f16
  unsigned short* Vtb    = (unsigned short*)(ws + 58720256);   // [4,16,64,2048] f16 (j-permuted)

  convert_f32_f16<<<(8192 * 1024 / 4 + 255) / 256, 256, 0, stream>>>(x, xh, 8192 * 1024 / 4);
  transpose_f32_f16<<<dim3(3072 / 32, 1024 / 32), dim3(32, 8), 0, stream>>>(W_qkv, Wqkv_t, 1024, 3072);
  transpose_f32_f16<<<dim3(1024 / 32, 1024 / 32), dim3(32, 8), 0, stream>>>(W_out, Wout_t, 1024, 1024);
  gemm_bt<<<dim3(3072 / 128, 8192 / 128), 256, 0, stream>>>(
      xh, Wqkv_t, 8192, 3072, 1024, 0, b_qkv, nullptr, Qb, Kb, Vtb);
  attn_kernel<<<4 * NHEADS * (S_LEN / 64), 256, 0, stream>>>(Qb, Kb, Vtb, rel_bias, ctxh);
  gemm_bt<<<dim3(1024 / 128, 8192 / 128), 256, 0, stream>>>(
      ctxh, Wout_t, 8192, 1024, 1024, 1, b_out, out, nullptr, nullptr, nullptr);
}

// Round 3
// 315.270 us; speedup vs baseline: 1.2730x; 1.0141x over previous
//
#include <hip/hip_runtime.h>

#define S_LEN 2048
#define NHEADS 16
#define DK 64
#define DMODEL 1024
#define QSCALE 0.18033688011f  /* 0.125 * log2(e) */

typedef float f32x4 __attribute__((ext_vector_type(4)));
typedef _Float16 f16x8 __attribute__((ext_vector_type(8)));
typedef _Float16 f16x4 __attribute__((ext_vector_type(4)));
typedef __fp16 h16x2 __attribute__((ext_vector_type(2)));   // cvt_pkrtz native type

__device__ __forceinline__ unsigned short f2h_bits(float f) {
  _Float16 h = (_Float16)f;
  unsigned short u; __builtin_memcpy(&u, &h, 2); return u;
}

__device__ __forceinline__ f32x4 mfma16(f16x8 a, f16x8 b, f32x4 c) {
  return __builtin_amdgcn_mfma_f32_16x16x32_f16(a, b, c, 0, 0, 0);
}
__device__ __forceinline__ f16x8 frag_ld(const unsigned short* p) {
  return *(const f16x8*)p;
}

#define GLD_LDS(g, l)                                                          \
  __builtin_amdgcn_global_load_lds(                                            \
      (const __attribute__((address_space(1))) void*)(g),                      \
      (__attribute__((address_space(3))) void*)(l), 16, 0, 0)

// raw barrier / counted waits (no compiler-implicit vmcnt(0) drain)
#define SBAR()  asm volatile("s_barrier" ::: "memory")
#define WAITV8  asm volatile("s_waitcnt vmcnt(8)" ::: "memory")
#define WAITV0  asm volatile("s_waitcnt vmcnt(0)" ::: "memory")
#define WAITL0  asm volatile("s_waitcnt lgkmcnt(0)" ::: "memory")

// ---------------- fp32 -> fp16 convert (contiguous) ----------------
__global__ void convert_f32_f16(const float* __restrict__ in,
                                unsigned short* __restrict__ out, int n4) {
  int i = blockIdx.x * blockDim.x + threadIdx.x;
  if (i < n4) {
    f32x4 v = *(const f32x4*)(in + (size_t)i * 4);
    unsigned short o[4];
#pragma unroll
    for (int j = 0; j < 4; j++) o[j] = f2h_bits(v[j]);
    *(uint2*)(out + (size_t)i * 4) = *(const uint2*)o;
  }
}

// ---------------- fp32 -> fp16 transpose ----------------
__global__ void transpose_f32_f16(const float* __restrict__ in,
                                  unsigned short* __restrict__ out, int R, int C) {
  __shared__ unsigned short tile[32][33];
  int bx = blockIdx.x * 32, by = blockIdx.y * 32;
  int tx = threadIdx.x, ty = threadIdx.y;
  for (int i = ty; i < 32; i += 8)
    tile[i][tx] = f2h_bits(in[(size_t)(by + i) * C + bx + tx]);
  __syncthreads();
  for (int i = ty; i < 32; i += 8)
    out[(size_t)(bx + i) * R + by + tx] = tile[tx][i];
}

// ---------------- 128x128 MFMA GEMM, B^T input (m97 structure), fp16 in fp32 acc
// + T1: bijective XCD-chunked block swizzle (nwg % 8 == 0 for both launches) so
//   each XCD's L2 holds a contiguous tile region (out-proj: A-panel 2MB + B 2MB
//   fits the 4MB XCD L2 exactly).
// V epilogue writes the within-32-block j-permutation pos = 32sb+8g+4jsub+r
// (from j = 32sb+16jsub+4g+r) so attn's PV B-frags are contiguous 16B reads.
__launch_bounds__(256)
__global__ void gemm_bt(const unsigned short* __restrict__ A,
                        const unsigned short* __restrict__ Bt,
                        int M, int N, int K, int mode,
                        const float* __restrict__ bias,
                        float* __restrict__ out0,
                        unsigned short* __restrict__ q_o,
                        unsigned short* __restrict__ k_o,
                        unsigned short* __restrict__ v_o) {
  __shared__ __attribute__((aligned(16))) unsigned short As[128 * 32];
  __shared__ __attribute__((aligned(16))) unsigned short Bs[128 * 32];
  const int tid = threadIdx.x;
  const int w = tid >> 6, lane = tid & 63;
  const int wm = w >> 1, wn = w & 1;
  const int col = lane & 15, quad = lane >> 4;
  // XCD-chunked swizzle: original ids {k, k+8, ...} (same XCD) -> contiguous tiles
  const int nx = gridDim.x;
  const int nwg = nx * gridDim.y;
  const int bidl = blockIdx.y * nx + blockIdx.x;
  const int cpx = nwg >> 3;
  const int swz = (bidl & 7) * cpx + (bidl >> 3);
  const int m0 = (swz / nx) * 128, n0 = (swz % nx) * 128;
  const f32x4 fzero = {0.f, 0.f, 0.f, 0.f};
  f32x4 acc[4][4];
#pragma unroll
  for (int i = 0; i < 4; i++)
#pragma unroll
    for (int j = 0; j < 4; j++) acc[i][j] = fzero;

  for (int k0 = 0; k0 < K; k0 += 32) {
    __syncthreads();
#pragma unroll
    for (int it = 0; it < 2; it++) {
      int c = it * 256 + tid;  // 512 16B-chunks per 128x32 tile
      GLD_LDS(A + (size_t)(m0 + (c >> 2)) * K + k0 + (c & 3) * 8, &As[c * 8]);
      GLD_LDS(Bt + (size_t)(n0 + (c >> 2)) * K + k0 + (c & 3) * 8, &Bs[c * 8]);
    }
    __syncthreads();
    f16x8 af[4], bfr[4];
#pragma unroll
    for (int mi = 0; mi < 4; mi++)
      af[mi] = frag_ld(&As[(wm * 64 + mi * 16 + col) * 32 + quad * 8]);
#pragma unroll
    for (int ni = 0; ni < 4; ni++)
      bfr[ni] = frag_ld(&Bs[(wn * 64 + ni * 16 + col) * 32 + quad * 8]);
#pragma unroll
    for (int mi = 0; mi < 4; mi++)
#pragma unroll
      for (int ni = 0; ni < 4; ni++)
        acc[mi][ni] = mfma16(af[mi], bfr[ni], acc[mi][ni]);
  }

#pragma unroll
  for (int mi = 0; mi < 4; mi++) {
#pragma unroll
    for (int ni = 0; ni < 4; ni++) {
      int gm_b = m0 + wm * 64 + mi * 16 + quad * 4;
      int gn = n0 + wn * 64 + ni * 16 + col;
      float bv = bias[gn];
      if (mode == 1) {
#pragma unroll
        for (int r = 0; r < 4; r++)
          out0[(size_t)(gm_b + r) * N + gn] = acc[mi][ni][r] + bv;
      } else {
        int b = gm_b >> 11, s0 = gm_b & 2047;    // M = 4*2048, s0..s0+3 same b
        int t = gn >> 10, hd = gn & 1023;        // N = 3*1024
        int h = hd >> 6, d = hd & 63;
        size_t bh = (size_t)(b * NHEADS + h);
        if (t == 2) {
          // permuted V store: s0 = 32sb+16jsub+4g -> pos0 = 32sb+8g+4jsub
          int pos0 = (s0 & ~31) | ((s0 & 12) << 1) | ((s0 & 16) >> 2);
          unsigned short o4[4];
#pragma unroll
          for (int r = 0; r < 4; r++) o4[r] = f2h_bits(acc[mi][ni][r] + bv);
          *(uint2*)&v_o[(bh * DK + d) * S_LEN + pos0] = *(const uint2*)o4;
        } else {
          unsigned short* dst = (t == 0) ? q_o : k_o;
          float sc = (t == 0) ? QSCALE : 1.0f;
#pragma unroll
          for (int r = 0; r < 4; r++)
            dst[(bh * S_LEN + s0 + r) * DK + d] = f2h_bits((acc[mi][ni][r] + bv) * sc);
        }
      }
    }
  }
}

// ---------------- flash attention: 32-j-per-wave, dbuf LDS, counted vmcnt ----
// Chunk = 128 j; 4 waves each own a private 32-j slice. K/V LDS DOUBLE-buffered:
// chunk ck+1's 8 global_load_lds are issued before computing ck, and the
// barrier uses a counted s_waitcnt vmcnt(8) (raw s_barrier, never a full
// vmcnt(0) drain in steady state) -> L2 latency hides under COMPUTE. This
// removes the per-chunk serial {drain + load-latency} that capped round 2 at
// MfmaUtil 24%.  PV is full-rate 16x16x32 via the lane-local k-permutation
//   pi(quad*8+e) = (e>>2)*16 + quad*4 + (e&3)
// with V j-permuted at the QKV-GEMM epilogue so B-frags are single 16B reads.
// XOR group-swizzle on K/V LDS (pre-swizzled global source + swizzled read).
// Max-free log2-domain softmax; bias via MFMA C-operand; cross-wave o/l
// reduction via LDS at block end. XCD swizzle for K/V L2 locality.
__launch_bounds__(256, 2)
__global__ void attn_kernel(const unsigned short* __restrict__ Q,
                            const unsigned short* __restrict__ K,
                            const unsigned short* __restrict__ Vt,
                            const float* __restrict__ rel_bias,
                            unsigned short* __restrict__ ctx) {
  __shared__ __attribute__((aligned(16))) char smem[74240];
  unsigned short* KsA = (unsigned short*)smem;              // 16 KB
  unsigned short* VsA = (unsigned short*)(smem + 16384);    // 16 KB
  unsigned short* KsB = (unsigned short*)(smem + 32768);    // 16 KB
  unsigned short* VsB = (unsigned short*)(smem + 49152);    // 16 KB
  float* brev = (float*)(smem + 65536);                     // 2112 f32 bias table
  float* lred = (float*)(smem + 73984);                     // 64 f32
  float* red  = (float*)smem;                               // epilogue alias (17408 B)

  const int tid = threadIdx.x;
  const int w = tid >> 6, lane = tid & 63;
  const int col = lane & 15, quad = lane >> 4;
  const int c7 = col & 7;
  const int bid = blockIdx.x;
  const int xcd = bid & 7, slot = bid >> 3;
  const int bh = (slot >> 5) * 8 + xcd;     // 8 bh per XCD (K/V set = 4MB = L2)
  const int qt = slot & 31;
  const int h = bh & (NHEADS - 1), b = bh >> 4;
  const unsigned short* qp = Q + (size_t)bh * S_LEN * DK;
  const unsigned short* kp = K + (size_t)bh * S_LEN * DK;
  const unsigned short* vp = Vt + (size_t)bh * DK * S_LEN;
  const f32x4 fzero = {0.f, 0.f, 0.f, 0.f};

  // windowed reversed bias table (log2e-scaled), idx = j - (q - qt*64) + 63
  const int tbase = 1985 - qt * 64;
#pragma unroll
  for (int it = 0; it < 9; it++) {
    int idx = it * 256 + tid;
    if (idx < 2112) {
      int rel = 3072 - (tbase + idx);
      rel = rel < 0 ? 0 : (rel > 2048 ? 2048 : rel);
      brev[idx] = rel_bias[rel * NHEADS + h] * 1.44269504089f;
    }
  }

  // Q as B-operand frags: qb[qs][ks], q = qt*64 + qs*16 + col
  f16x8 qb[4][2];
#pragma unroll
  for (int qs = 0; qs < 4; qs++)
#pragma unroll
    for (int ks = 0; ks < 2; ks++)
      qb[qs][ks] = frag_ld(qp + (size_t)(qt * 64 + qs * 16 + col) * DK + ks * 32 + quad * 8);

  f32x4 o[4][4];      // partial o[q=qs*16+quad*4+r][d=ds*16+col] over wave's 32 j
  float rsum[4];      // partial l[q=qs*16+col] over lane's j
#pragma unroll
  for (int qs = 0; qs < 4; qs++) {
#pragma unroll
    for (int ds = 0; ds < 4; ds++) o[qs][ds] = fzero;
    rsum[qs] = 0.f;
  }

  // ---- LDS read offsets (per-lane constants, elements) ----
  int kaoff[2][2];
#pragma unroll
  for (int jsub = 0; jsub < 2; jsub++)
#pragma unroll
    for (int ks = 0; ks < 2; ks++)
      kaoff[jsub][ks] = (w * 32 + jsub * 16 + col) * 64 + (((ks * 4 + quad) ^ c7) * 8);
  const int vg = w * 4 + quad;
  const int vboff = col * 128 + (((vg & 8) | ((vg & 7) ^ c7)) * 8);  // + ds*2048

  // ---- staging addresses ----
  const int rK = tid >> 3, gK = (tid & 7) ^ (rK & 7);
  const int dV = tid >> 4, gsV = tid & 15;
  const int gV = (gsV & 8) | ((gsV & 7) ^ (dV & 7));
  const unsigned short* ks0 = kp + rK * DK + gK * 8;
  const unsigned short* vs0 = vp + (size_t)dV * S_LEN + gV * 8;
  unsigned short* kdA = &KsA[tid * 8];
  unsigned short* vdA = &VsA[tid * 8];
  unsigned short* kdB = &KsB[tid * 8];
  unsigned short* vdB = &VsB[tid * 8];

  // bias: idx = ck*128 + w*32 + jsub*16 + quad*4 + r - (qs*16 + col) + 63
  const float* bq = brev + (w * 32 + quad * 4 - col + 63);

#define ISSUE8(kd, vd)                                                         \
  _Pragma("unroll")                                                            \
  for (int it = 0; it < 4; it++) {                                             \
    GLD_LDS(ks0 + it * 32 * DK, kd + it * 2048);                               \
    GLD_LDS(vs0 + (size_t)it * 16 * S_LEN, vd + it * 2048);                    \
  }                                                                            \
  ks0 += 128 * DK; vs0 += 128;

#define COMPUTE(ka, vb)                                                        \
  _Pragma("unroll")                                                            \
  for (int qs = 0; qs < 4; qs++) {                                             \
    h16x2 pk[4];                                                               \
    _Pragma("unroll")                                                          \
    for (int js = 0; js < 2; js++) {                                           \
      f32x4 bias4;                                                             \
      _Pragma("unroll")                                                        \
      for (int r = 0; r < 4; r++) bias4[r] = bq[(js - qs) * 16 + r];           \
      f32x4 sc = mfma16(ka[js][1], qb[qs][1],                                  \
                        mfma16(ka[js][0], qb[qs][0], bias4));                  \
      float p0 = __builtin_amdgcn_exp2f(sc[0]);                                \
      float p1 = __builtin_amdgcn_exp2f(sc[1]);                                \
      float p2 = __builtin_amdgcn_exp2f(sc[2]);                                \
      float p3 = __builtin_amdgcn_exp2f(sc[3]);                                \
      rsum[qs] += (p0 + p1) + (p2 + p3);                                       \
      pk[js * 2]     = __builtin_amdgcn_cvt_pkrtz(p0, p1);                     \
      pk[js * 2 + 1] = __builtin_amdgcn_cvt_pkrtz(p2, p3);                     \
    }                                                                          \
    f16x8 pa;                                                                  \
    __builtin_memcpy(&pa, pk, 16);                                             \
    _Pragma("unroll")                                                          \
    for (int ds = 0; ds < 4; ds++)                                             \
      o[qs][ds] = mfma16(pa, vb[ds], o[qs][ds]);                               \
  }

#define PHASE(Ksb, Vsb)                                                        \
  {                                                                            \
    f16x8 ka[2][2];                                                            \
    _Pragma("unroll")                                                          \
    for (int jsub = 0; jsub < 2; jsub++)                                       \
      _Pragma("unroll")                                                        \
      for (int ks = 0; ks < 2; ks++)                                           \
        ka[jsub][ks] = frag_ld(&Ksb[kaoff[jsub][ks]]);                         \
    f16x8 vb[4];                                                               \
    _Pragma("unroll")                                                          \
    for (int ds = 0; ds < 4; ds++)                                             \
      vb[ds] = frag_ld(&Vsb[vboff + ds * 2048]);                               \
    COMPUTE(ka, vb)                                                            \
    bq += 128;                                                                 \
  }

  ISSUE8(kdA, vdA)                 // chunk 0 -> A
  __syncthreads();                 // brev visible + full drain (once)

  for (int ck = 0; ck < 16; ck += 2) {
    // even: prefetch ck+1 -> B, compute ck from A
    ISSUE8(kdB, vdB)
    WAITV8;                        // my chunk-ck (A) loads landed
    SBAR();                        // everyone's A loads landed
    PHASE(KsA, VsA)
    WAITL0;                        // my LDS reads of A retired
    SBAR();                        // all waves done reading A
    // odd: prefetch ck+2 -> A (except last), compute ck+1 from B
    if (ck < 14) {
      ISSUE8(kdA, vdA)
      WAITV8;
    } else {
      WAITV0;
    }
    SBAR();
    PHASE(KsB, VsB)
    WAITL0;
    SBAR();
  }

  // finish l: sum over quads (j within wave) -> all lanes of col hold wave-partial l[q]
#pragma unroll
  for (int qs = 0; qs < 4; qs++) {
    rsum[qs] += __shfl_xor(rsum[qs], 16);
    rsum[qs] += __shfl_xor(rsum[qs], 32);
  }

  // cross-wave reduction (sequential, in-place; red stride 68 for alignment+banks)
  __syncthreads();
  for (int ws = 3; ws >= 0; ws--) {
    if (w == ws) {
#pragma unroll
      for (int qs = 0; qs < 4; qs++) {
#pragma unroll
        for (int ds = 0; ds < 4; ds++) {
#pragma unroll
          for (int r = 0; r < 4; r++) {
            int q = qs * 16 + quad * 4 + r, d = ds * 16 + col;
            if (ws == 3) red[q * 68 + d] = o[qs][ds][r];
            else         red[q * 68 + d] += o[qs][ds][r];
          }
        }
        int ql = qs * 16 + col;
        if (ws == 3) lred[ql] = rsum[qs];
        else         lred[ql] += rsum[qs];
      }
    }
    __syncthreads();
  }

  // cooperative readout: wave w handles q rows [w*16, w*16+16)
#pragma unroll
  for (int pass = 0; pass < 4; pass++) {
    int ql = w * 16 + pass * 4 + quad;
    f32x4 ov = *(const f32x4*)&red[ql * 68 + col * 4];
    float inv = 1.0f / lred[ql];
    h16x2 lo = __builtin_amdgcn_cvt_pkrtz(ov[0] * inv, ov[1] * inv);
    h16x2 hi = __builtin_amdgcn_cvt_pkrtz(ov[2] * inv, ov[3] * inv);
    uint2 pkd;
    __builtin_memcpy(&pkd.x, &lo, 4);
    __builtin_memcpy(&pkd.y, &hi, 4);
    *(uint2*)&ctx[((size_t)b * S_LEN + qt * 64 + ql) * DMODEL + h * DK + col * 4] = pkd;
  }
}

extern "C" void kernel_launch(void* const* d_in, const int* in_sizes, int n_in,
                              void* d_out, int out_size, void* d_ws, size_t ws_size,
                              hipStream_t stream) {
  (void)in_sizes; (void)n_in; (void)out_size; (void)ws_size;
  const float* x        = (const float*)d_in[0];
  const float* W_qkv    = (const float*)d_in[1];
  const float* b_qkv    = (const float*)d_in[2];
  const float* W_out    = (const float*)d_in[3];
  const float* b_out    = (const float*)d_in[4];
  const float* rel_bias = (const float*)d_in[5];
  float* out = (float*)d_out;

  char* ws = (char*)d_ws;
  unsigned short* xh     = (unsigned short*)(ws + 0);          // [8192,1024] f16 (aliases ctx)
  unsigned short* ctxh   = (unsigned short*)(ws + 0);
  unsigned short* Wqkv_t = (unsigned short*)(ws + 16777216);   // [3072,1024] f16
  unsigned short* Wout_t = (unsigned short*)(ws + 23068672);   // [1024,1024] f16
  unsigned short* Qb     = (unsigned short*)(ws + 25165824);   // [4,16,2048,64] f16
  unsigned short* Kb     = (unsigned short*)(ws + 41943040);   // [4,16,2048,64] f16
  unsigned short* Vtb    = (unsigned short*)(ws + 58720256);   // [4,16,64,2048] f16 (j-permuted)

  convert_f32_f16<<<(8192 * 1024 / 4 + 255) / 256, 256, 0, stream>>>(x, xh, 8192 * 1024 / 4);
  transpose_f32_f16<<<dim3(3072 / 32, 1024 / 32), dim3(32, 8), 0, stream>>>(W_qkv, Wqkv_t, 1024, 3072);
  transpose_f32_f16<<<dim3(1024 / 32, 1024 / 32), dim3(32, 8), 0, stream>>>(W_out, Wout_t, 1024, 1024);
  gemm_bt<<<dim3(3072 / 128, 8192 / 128), 256, 0, stream>>>(
      xh, Wqkv_t, 8192, 3072, 1024, 0, b_qkv, nullptr, Qb, Kb, Vtb);
  attn_kernel<<<4 * NHEADS * (S_LEN / 64), 256, 0, stream>>>(Qb, Kb, Vtb, rel_bias, ctxh);
  gemm_bt<<<dim3(1024 / 128, 8192 / 128), 256, 0, stream>>>(
      ctxh, Wout_t, 8192, 1024, 1024, 1, b_out, out, nullptr, nullptr, nullptr);
}

// Round 4
// 312.810 us; speedup vs baseline: 1.2830x; 1.0079x over previous
//
#include <hip/hip_runtime.h>

#define S_LEN 2048
#define NHEADS 16
#define DK 64
#define DMODEL 1024
#define QSCALE 0.18033688011f  /* 0.125 * log2(e) */

typedef float f32x4 __attribute__((ext_vector_type(4)));
typedef _Float16 f16x8 __attribute__((ext_vector_type(8)));
typedef _Float16 f16x4 __attribute__((ext_vector_type(4)));
typedef __fp16 h16x2 __attribute__((ext_vector_type(2)));   // cvt_pkrtz native type

__device__ __forceinline__ unsigned short f2h_bits(float f) {
  _Float16 h = (_Float16)f;
  unsigned short u; __builtin_memcpy(&u, &h, 2); return u;
}

__device__ __forceinline__ f32x4 mfma16(f16x8 a, f16x8 b, f32x4 c) {
  return __builtin_amdgcn_mfma_f32_16x16x32_f16(a, b, c, 0, 0, 0);
}
__device__ __forceinline__ f16x8 frag_ld(const unsigned short* p) {
  return *(const f16x8*)p;
}

#define GLD_LDS(g, l)                                                          \
  __builtin_amdgcn_global_load_lds(                                            \
      (const __attribute__((address_space(1))) void*)(g),                      \
      (__attribute__((address_space(3))) void*)(l), 16, 0, 0)

// ---------------- fp32 -> fp16 convert (contiguous) ----------------
__global__ void convert_f32_f16(const float* __restrict__ in,
                                unsigned short* __restrict__ out, int n4) {
  int i = blockIdx.x * blockDim.x + threadIdx.x;
  if (i < n4) {
    f32x4 v = *(const f32x4*)(in + (size_t)i * 4);
    unsigned short o[4];
#pragma unroll
    for (int j = 0; j < 4; j++) o[j] = f2h_bits(v[j]);
    *(uint2*)(out + (size_t)i * 4) = *(const uint2*)o;
  }
}

// ---------------- fp32 -> fp16 transpose ----------------
__global__ void transpose_f32_f16(const float* __restrict__ in,
                                  unsigned short* __restrict__ out, int R, int C) {
  __shared__ unsigned short tile[32][33];
  int bx = blockIdx.x * 32, by = blockIdx.y * 32;
  int tx = threadIdx.x, ty = threadIdx.y;
  for (int i = ty; i < 32; i += 8)
    tile[i][tx] = f2h_bits(in[(size_t)(by + i) * C + bx + tx]);
  __syncthreads();
  for (int i = ty; i < 32; i += 8)
    out[(size_t)(bx + i) * R + by + tx] = tile[tx][i];
}

// ---------------- 128x128 MFMA GEMM, B^T input (m97 structure), fp16 in fp32 acc
// + T1 bijective XCD-chunked block swizzle.
// Epilogue writes attn-fragment-native layouts so attn loads K/V frags DIRECTLY
// from global, fully coalesced (no LDS, no barriers there):
//   K: [bh][jblk=s>>5][khalf=d>>5][s&31][d&31]
//   V: [bh][pblk=s>>5][d][p]  with within-32 j-permutation p = 8g+4jsub+r
//      (from s&31 = 16jsub+4g+r) so PV B-frags are contiguous 16B.
__launch_bounds__(256)
__global__ void gemm_bt(const unsigned short* __restrict__ A,
                        const unsigned short* __restrict__ Bt,
                        int M, int N, int K, int mode,
                        const float* __restrict__ bias,
                        float* __restrict__ out0,
                        unsigned short* __restrict__ q_o,
                        unsigned short* __restrict__ k_o,
                        unsigned short* __restrict__ v_o) {
  __shared__ __attribute__((aligned(16))) unsigned short As[128 * 32];
  __shared__ __attribute__((aligned(16))) unsigned short Bs[128 * 32];
  const int tid = threadIdx.x;
  const int w = tid >> 6, lane = tid & 63;
  const int wm = w >> 1, wn = w & 1;
  const int col = lane & 15, quad = lane >> 4;
  // XCD-chunked swizzle: original ids {k, k+8, ...} (same XCD) -> contiguous tiles
  const int nx = gridDim.x;
  const int nwg = nx * gridDim.y;
  const int bidl = blockIdx.y * nx + blockIdx.x;
  const int cpx = nwg >> 3;
  const int swz = (bidl & 7) * cpx + (bidl >> 3);
  const int m0 = (swz / nx) * 128, n0 = (swz % nx) * 128;
  const f32x4 fzero = {0.f, 0.f, 0.f, 0.f};
  f32x4 acc[4][4];
#pragma unroll
  for (int i = 0; i < 4; i++)
#pragma unroll
    for (int j = 0; j < 4; j++) acc[i][j] = fzero;

  for (int k0 = 0; k0 < K; k0 += 32) {
    __syncthreads();
#pragma unroll
    for (int it = 0; it < 2; it++) {
      int c = it * 256 + tid;  // 512 16B-chunks per 128x32 tile
      GLD_LDS(A + (size_t)(m0 + (c >> 2)) * K + k0 + (c & 3) * 8, &As[c * 8]);
      GLD_LDS(Bt + (size_t)(n0 + (c >> 2)) * K + k0 + (c & 3) * 8, &Bs[c * 8]);
    }
    __syncthreads();
    f16x8 af[4], bfr[4];
#pragma unroll
    for (int mi = 0; mi < 4; mi++)
      af[mi] = frag_ld(&As[(wm * 64 + mi * 16 + col) * 32 + quad * 8]);
#pragma unroll
    for (int ni = 0; ni < 4; ni++)
      bfr[ni] = frag_ld(&Bs[(wn * 64 + ni * 16 + col) * 32 + quad * 8]);
#pragma unroll
    for (int mi = 0; mi < 4; mi++)
#pragma unroll
      for (int ni = 0; ni < 4; ni++)
        acc[mi][ni] = mfma16(af[mi], bfr[ni], acc[mi][ni]);
  }

#pragma unroll
  for (int mi = 0; mi < 4; mi++) {
#pragma unroll
    for (int ni = 0; ni < 4; ni++) {
      int gm_b = m0 + wm * 64 + mi * 16 + quad * 4;
      int gn = n0 + wn * 64 + ni * 16 + col;
      float bv = bias[gn];
      if (mode == 1) {
#pragma unroll
        for (int r = 0; r < 4; r++)
          out0[(size_t)(gm_b + r) * N + gn] = acc[mi][ni][r] + bv;
      } else {
        int b = gm_b >> 11, s0 = gm_b & 2047;    // M = 4*2048, s0..s0+3 same b
        int t = gn >> 10, hd = gn & 1023;        // N = 3*1024
        int h = hd >> 6, d = hd & 63;
        size_t bh = (size_t)(b * NHEADS + h);
        if (t == 2) {
          // V: [bh][pblk][d][p], p0 = 8g+4jsub from s0&31 = 16jsub+4g
          int p0 = ((s0 & 12) << 1) | ((s0 & 16) >> 2);
          unsigned short o4[4];
#pragma unroll
          for (int r = 0; r < 4; r++) o4[r] = f2h_bits(acc[mi][ni][r] + bv);
          *(uint2*)&v_o[bh * (DK * S_LEN) + (s0 >> 5) * 2048 + d * 32 + p0] =
              *(const uint2*)o4;
        } else if (t == 0) {
#pragma unroll
          for (int r = 0; r < 4; r++)
            q_o[(bh * S_LEN + s0 + r) * DK + d] =
                f2h_bits((acc[mi][ni][r] + bv) * QSCALE);
        } else {
          // K: [bh][jblk][khalf][j&31][k&31]
          size_t kb = bh * (DK * S_LEN) + (s0 >> 5) * 2048 + (d >> 5) * 1024 +
                      (s0 & 31) * 32 + (d & 31);
#pragma unroll
          for (int r = 0; r < 4; r++)
            k_o[kb + r * 32] = f2h_bits(acc[mi][ni][r] + bv);
        }
      }
    }
  }
}

// ---------------- flash attention: barrier-free, LDS-free K/V, reg dbuf ------
// Chunk = 128 j; 4 waves each own a private 32-j slice. K and V are stored by
// the QKV GEMM in fragment-native per-32-block layouts, so each MFMA operand
// is ONE fully-coalesced 64-lane b128 load (16 consecutive 64B rows) straight
// into registers. No K/V LDS, no main-loop barriers: each wave is an
// independent pipeline, register-double-buffered one chunk ahead (8 loads in
// flight; compiler inserts minimal vmcnt waits - no barrier forces a drain).
// PV is full-rate 16x16x32 via the lane-local k-permutation
//   pi(quad*8+e) = (e>>2)*16 + quad*4 + (e&3)
// matched by the V j-permutation done in the GEMM epilogue.
// Max-free log2-domain softmax; bias via MFMA C-operand (20 dedup'd LDS b32
// per wave-chunk); cross-wave o/l reduction via LDS at block end. XCD swizzle
// keeps each bh's K/V pinned to one XCD's L2.
__launch_bounds__(256, 2)
__global__ void attn_kernel(const unsigned short* __restrict__ Q,
                            const unsigned short* __restrict__ K,
                            const unsigned short* __restrict__ Vt,
                            const float* __restrict__ rel_bias,
                            unsigned short* __restrict__ ctx) {
  __shared__ __attribute__((aligned(16))) char smem[17664];
  float* brev = (float*)smem;              // 2112 f32 bias table (dead after loop)
  float* red  = (float*)smem;              // 64*68 f32 epilogue scratch (aliases brev)
  float* lred = (float*)(smem + 17408);    // 64 f32

  const int tid = threadIdx.x;
  const int w = tid >> 6, lane = tid & 63;
  const int col = lane & 15, quad = lane >> 4;
  const int bid = blockIdx.x;
  const int xcd = bid & 7, slot = bid >> 3;
  const int bh = (slot >> 5) * 8 + xcd;     // 8 bh per XCD (K/V set = 4MB = L2)
  const int qt = slot & 31;
  const int h = bh & (NHEADS - 1), b = bh >> 4;
  const unsigned short* qp = Q + (size_t)bh * S_LEN * DK;
  const f32x4 fzero = {0.f, 0.f, 0.f, 0.f};

  // windowed reversed bias table (log2e-scaled), idx = j - (q - qt*64) + 63
  const int tbase = 1985 - qt * 64;
#pragma unroll
  for (int it = 0; it < 9; it++) {
    int idx = it * 256 + tid;
    if (idx < 2112) {
      int rel = 3072 - (tbase + idx);
      rel = rel < 0 ? 0 : (rel > 2048 ? 2048 : rel);
      brev[idx] = rel_bias[rel * NHEADS + h] * 1.44269504089f;
    }
  }

  // Q as B-operand frags: qb[qs][ks], q = qt*64 + qs*16 + col
  f16x8 qb[4][2];
#pragma unroll
  for (int qs = 0; qs < 4; qs++)
#pragma unroll
    for (int ks = 0; ks < 2; ks++)
      qb[qs][ks] = frag_ld(qp + (size_t)(qt * 64 + qs * 16 + col) * DK + ks * 32 + quad * 8);

  f32x4 o[4][4];      // partial o[q=qs*16+quad*4+r][d=ds*16+col] over wave's 32 j
  float rsum[4];      // partial l[q=qs*16+col] over lane's j
#pragma unroll
  for (int qs = 0; qs < 4; qs++) {
#pragma unroll
    for (int ds = 0; ds < 4; ds++) o[qs][ds] = fzero;
    rsum[qs] = 0.f;
  }

  // per-lane fragment base inside a 32-block (2048 elems): row*32 + quad*8
  const int koff = col * 32 + quad * 8;
  const unsigned short* kptr = K + (size_t)bh * (DK * S_LEN) + w * 2048 + koff;
  const unsigned short* vptr = Vt + (size_t)bh * (DK * S_LEN) + w * 2048 + koff;
  // bias: idx = ck*128 + w*32 + jsub*16 + quad*4 + r - (qs*16 + col) + 63
  const float* bq = brev + (w * 32 + quad * 4 - col + 63);

  __syncthreads();  // brev ready

#define LOADK(dst, p)                                                          \
  dst[0][0] = frag_ld(p);                                                      \
  dst[0][1] = frag_ld(p + 1024);                                               \
  dst[1][0] = frag_ld(p + 512);                                                \
  dst[1][1] = frag_ld(p + 1536);

#define LOADV(dst, p)                                                          \
  _Pragma("unroll")                                                            \
  for (int ds = 0; ds < 4; ds++) dst[ds] = frag_ld(p + ds * 512);

#define COMPUTE(ka, vb)                                                        \
  {                                                                            \
    float bb[20];                                                              \
    _Pragma("unroll")                                                          \
    for (int g = 0; g < 5; g++)                                                \
      _Pragma("unroll")                                                        \
      for (int r = 0; r < 4; r++) bb[g * 4 + r] = bq[(g - 3) * 16 + r];        \
    _Pragma("unroll")                                                          \
    for (int qs = 0; qs < 4; qs++) {                                           \
      h16x2 pk[4];                                                             \
      _Pragma("unroll")                                                        \
      for (int js = 0; js < 2; js++) {                                         \
        f32x4 bias4;                                                           \
        _Pragma("unroll")                                                      \
        for (int r = 0; r < 4; r++) bias4[r] = bb[(js - qs + 3) * 4 + r];      \
        f32x4 sc = mfma16(ka[js][1], qb[qs][1],                                \
                          mfma16(ka[js][0], qb[qs][0], bias4));                \
        float p0 = __builtin_amdgcn_exp2f(sc[0]);                              \
        float p1 = __builtin_amdgcn_exp2f(sc[1]);                              \
        float p2 = __builtin_amdgcn_exp2f(sc[2]);                              \
        float p3 = __builtin_amdgcn_exp2f(sc[3]);                              \
        rsum[qs] += (p0 + p1) + (p2 + p3);                                     \
        pk[js * 2]     = __builtin_amdgcn_cvt_pkrtz(p0, p1);                   \
        pk[js * 2 + 1] = __builtin_amdgcn_cvt_pkrtz(p2, p3);                   \
      }                                                                        \
      f16x8 pa;                                                                \
      __builtin_memcpy(&pa, pk, 16);                                           \
      _Pragma("unroll")                                                        \
      for (int ds = 0; ds < 4; ds++)                                           \
        o[qs][ds] = mfma16(pa, vb[ds], o[qs][ds]);                             \
    }                                                                          \
  }

  f16x8 kaA[2][2], kaB[2][2], vbA[4], vbB[4];
  LOADK(kaA, kptr) LOADV(vbA, vptr) kptr += 8192; vptr += 8192;   // chunk 0
  for (int ck = 0; ck < 16; ck += 2) {
    LOADK(kaB, kptr) LOADV(vbB, vptr) kptr += 8192; vptr += 8192; // chunk ck+1
    COMPUTE(kaA, vbA) bq += 128;
    if (ck < 14) {
      LOADK(kaA, kptr) LOADV(vbA, vptr) kptr += 8192; vptr += 8192; // chunk ck+2
    }
    COMPUTE(kaB, vbB) bq += 128;
  }

  // finish l: sum over quads (j within wave) -> all lanes of col hold wave-partial l[q]
#pragma unroll
  for (int qs = 0; qs < 4; qs++) {
    rsum[qs] += __shfl_xor(rsum[qs], 16);
    rsum[qs] += __shfl_xor(rsum[qs], 32);
  }

  // cross-wave reduction (sequential, in-place; red stride 68 for alignment+banks)
  __syncthreads();
  for (int ws = 3; ws >= 0; ws--) {
    if (w == ws) {
#pragma unroll
      for (int qs = 0; qs < 4; qs++) {
#pragma unroll
        for (int ds = 0; ds < 4; ds++) {
#pragma unroll
          for (int r = 0; r < 4; r++) {
            int q = qs * 16 + quad * 4 + r, d = ds * 16 + col;
            if (ws == 3) red[q * 68 + d] = o[qs][ds][r];
            else         red[q * 68 + d] += o[qs][ds][r];
          }
        }
        int ql = qs * 16 + col;
        if (ws == 3) lred[ql] = rsum[qs];
        else         lred[ql] += rsum[qs];
      }
    }
    __syncthreads();
  }

  // cooperative readout: wave w handles q rows [w*16, w*16+16)
#pragma unroll
  for (int pass = 0; pass < 4; pass++) {
    int ql = w * 16 + pass * 4 + quad;
    f32x4 ov = *(const f32x4*)&red[ql * 68 + col * 4];
    float inv = 1.0f / lred[ql];
    h16x2 lo = __builtin_amdgcn_cvt_pkrtz(ov[0] * inv, ov[1] * inv);
    h16x2 hi = __builtin_amdgcn_cvt_pkrtz(ov[2] * inv, ov[3] * inv);
    uint2 pkd;
    __builtin_memcpy(&pkd.x, &lo, 4);
    __builtin_memcpy(&pkd.y, &hi, 4);
    *(uint2*)&ctx[((size_t)b * S_LEN + qt * 64 + ql) * DMODEL + h * DK + col * 4] = pkd;
  }
}

extern "C" void kernel_launch(void* const* d_in, const int* in_sizes, int n_in,
                              void* d_out, int out_size, void* d_ws, size_t ws_size,
                              hipStream_t stream) {
  (void)in_sizes; (void)n_in; (void)out_size; (void)ws_size;
  const float* x        = (const float*)d_in[0];
  const float* W_qkv    = (const float*)d_in[1];
  const float* b_qkv    = (const float*)d_in[2];
  const float* W_out    = (const float*)d_in[3];
  const float* b_out    = (const float*)d_in[4];
  const float* rel_bias = (const float*)d_in[5];
  float* out = (float*)d_out;

  char* ws = (char*)d_ws;
  unsigned short* xh     = (unsigned short*)(ws + 0);          // [8192,1024] f16 (aliases ctx)
  unsigned short* ctxh   = (unsigned short*)(ws + 0);
  unsigned short* Wqkv_t = (unsigned short*)(ws + 16777216);   // [3072,1024] f16
  unsigned short* Wout_t = (unsigned short*)(ws + 23068672);   // [1024,1024] f16
  unsigned short* Qb     = (unsigned short*)(ws + 25165824);   // [4,16,2048,64] f16
  unsigned short* Kb     = (unsigned short*)(ws + 41943040);   // [4,16,64blk,2,32,32] f16
  unsigned short* Vtb    = (unsigned short*)(ws + 58720256);   // [4,16,64blk,64,32] f16

  convert_f32_f16<<<(8192 * 1024 / 4 + 255) / 256, 256, 0, stream>>>(x, xh, 8192 * 1024 / 4);
  transpose_f32_f16<<<dim3(3072 / 32, 1024 / 32), dim3(32, 8), 0, stream>>>(W_qkv, Wqkv_t, 1024, 3072);
  transpose_f32_f16<<<dim3(1024 / 32, 1024 / 32), dim3(32, 8), 0, stream>>>(W_out, Wout_t, 1024, 1024);
  gemm_bt<<<dim3(3072 / 128, 8192 / 128), 256, 0, stream>>>(
      xh, Wqkv_t, 8192, 3072, 1024, 0, b_qkv, nullptr, Qb, Kb, Vtb);
  attn_kernel<<<4 * NHEADS * (S_LEN / 64), 256, 0, stream>>>(Qb, Kb, Vtb, rel_bias, ctxh);
  gemm_bt<<<dim3(1024 / 128, 8192 / 128), 256, 0, stream>>>(
      ctxh, Wout_t, 8192, 1024, 1024, 1, b_out, out, nullptr, nullptr, nullptr);
}

// Round 5
// 298.653 us; speedup vs baseline: 1.3438x; 1.0474x over previous
//
#include <hip/hip_runtime.h>

#define S_LEN 2048
#define NHEADS 16
#define DK 64
#define DMODEL 1024
#define QSCALE 0.18033688011f  /* 0.125 * log2(e) */

typedef float f32x4 __attribute__((ext_vector_type(4)));
typedef _Float16 f16x8 __attribute__((ext_vector_type(8)));
typedef _Float16 f16x4 __attribute__((ext_vector_type(4)));
typedef __fp16 h16x2 __attribute__((ext_vector_type(2)));   // cvt_pkrtz native type

__device__ __forceinline__ unsigned short f2h_bits(float f) {
  _Float16 h = (_Float16)f;
  unsigned short u; __builtin_memcpy(&u, &h, 2); return u;
}

__device__ __forceinline__ f32x4 mfma16(f16x8 a, f16x8 b, f32x4 c) {
  return __builtin_amdgcn_mfma_f32_16x16x32_f16(a, b, c, 0, 0, 0);
}
__device__ __forceinline__ f16x8 frag_ld(const unsigned short* p) {
  return *(const f16x8*)p;
}

#define GLD_LDS(g, l)                                                          \
  __builtin_amdgcn_global_load_lds(                                            \
      (const __attribute__((address_space(1))) void*)(g),                      \
      (__attribute__((address_space(3))) void*)(l), 16, 0, 0)

// ---------------- fp32 -> fp16 convert (contiguous) ----------------
__global__ void convert_f32_f16(const float* __restrict__ in,
                                unsigned short* __restrict__ out, int n4) {
  int i = blockIdx.x * blockDim.x + threadIdx.x;
  if (i < n4) {
    f32x4 v = *(const f32x4*)(in + (size_t)i * 4);
    unsigned short o[4];
#pragma unroll
    for (int j = 0; j < 4; j++) o[j] = f2h_bits(v[j]);
    *(uint2*)(out + (size_t)i * 4) = *(const uint2*)o;
  }
}

// ---------------- fp32 -> fp16 transpose ----------------
__global__ void transpose_f32_f16(const float* __restrict__ in,
                                  unsigned short* __restrict__ out, int R, int C) {
  __shared__ unsigned short tile[32][33];
  int bx = blockIdx.x * 32, by = blockIdx.y * 32;
  int tx = threadIdx.x, ty = threadIdx.y;
  for (int i = ty; i < 32; i += 8)
    tile[i][tx] = f2h_bits(in[(size_t)(by + i) * C + bx + tx]);
  __syncthreads();
  for (int i = ty; i < 32; i += 8)
    out[(size_t)(bx + i) * R + by + tx] = tile[tx][i];
}

// ---------------- 128x128 MFMA GEMM, B^T input (m97 structure), fp16 in fp32 acc
// + T1 bijective XCD-chunked block swizzle.
// Epilogue writes attn-fragment-native layouts so attn loads K/V frags DIRECTLY
// from global, fully coalesced (no LDS, no barriers there):
//   K: [bh][jblk=s>>5][khalf=d>>5][s&31][d&31]
//   V: [bh][pblk=s>>5][d][p]  with within-32 j-permutation p = 8g+4jsub+r
//      (from s&31 = 16jsub+4g+r) so PV B-frags are contiguous 16B.
__launch_bounds__(256)
__global__ void gemm_bt(const unsigned short* __restrict__ A,
                        const unsigned short* __restrict__ Bt,
                        int M, int N, int K, int mode,
                        const float* __restrict__ bias,
                        float* __restrict__ out0,
                        unsigned short* __restrict__ q_o,
                        unsigned short* __restrict__ k_o,
                        unsigned short* __restrict__ v_o) {
  __shared__ __attribute__((aligned(16))) unsigned short As[128 * 32];
  __shared__ __attribute__((aligned(16))) unsigned short Bs[128 * 32];
  const int tid = threadIdx.x;
  const int w = tid >> 6, lane = tid & 63;
  const int wm = w >> 1, wn = w & 1;
  const int col = lane & 15, quad = lane >> 4;
  // XCD-chunked swizzle: original ids {k, k+8, ...} (same XCD) -> contiguous tiles
  const int nx = gridDim.x;
  const int nwg = nx * gridDim.y;
  const int bidl = blockIdx.y * nx + blockIdx.x;
  const int cpx = nwg >> 3;
  const int swz = (bidl & 7) * cpx + (bidl >> 3);
  const int m0 = (swz / nx) * 128, n0 = (swz % nx) * 128;
  const f32x4 fzero = {0.f, 0.f, 0.f, 0.f};
  f32x4 acc[4][4];
#pragma unroll
  for (int i = 0; i < 4; i++)
#pragma unroll
    for (int j = 0; j < 4; j++) acc[i][j] = fzero;

  for (int k0 = 0; k0 < K; k0 += 32) {
    __syncthreads();
#pragma unroll
    for (int it = 0; it < 2; it++) {
      int c = it * 256 + tid;  // 512 16B-chunks per 128x32 tile
      GLD_LDS(A + (size_t)(m0 + (c >> 2)) * K + k0 + (c & 3) * 8, &As[c * 8]);
      GLD_LDS(Bt + (size_t)(n0 + (c >> 2)) * K + k0 + (c & 3) * 8, &Bs[c * 8]);
    }
    __syncthreads();
    f16x8 af[4], bfr[4];
#pragma unroll
    for (int mi = 0; mi < 4; mi++)
      af[mi] = frag_ld(&As[(wm * 64 + mi * 16 + col) * 32 + quad * 8]);
#pragma unroll
    for (int ni = 0; ni < 4; ni++)
      bfr[ni] = frag_ld(&Bs[(wn * 64 + ni * 16 + col) * 32 + quad * 8]);
#pragma unroll
    for (int mi = 0; mi < 4; mi++)
#pragma unroll
      for (int ni = 0; ni < 4; ni++)
        acc[mi][ni] = mfma16(af[mi], bfr[ni], acc[mi][ni]);
  }

#pragma unroll
  for (int mi = 0; mi < 4; mi++) {
#pragma unroll
    for (int ni = 0; ni < 4; ni++) {
      int gm_b = m0 + wm * 64 + mi * 16 + quad * 4;
      int gn = n0 + wn * 64 + ni * 16 + col;
      float bv = bias[gn];
      if (mode == 1) {
#pragma unroll
        for (int r = 0; r < 4; r++)
          out0[(size_t)(gm_b + r) * N + gn] = acc[mi][ni][r] + bv;
      } else {
        int b = gm_b >> 11, s0 = gm_b & 2047;    // M = 4*2048, s0..s0+3 same b
        int t = gn >> 10, hd = gn & 1023;        // N = 3*1024
        int h = hd >> 6, d = hd & 63;
        size_t bh = (size_t)(b * NHEADS + h);
        if (t == 2) {
          // V: [bh][pblk][d][p], p0 = 8g+4jsub from s0&31 = 16jsub+4g
          int p0 = ((s0 & 12) << 1) | ((s0 & 16) >> 2);
          unsigned short o4[4];
#pragma unroll
          for (int r = 0; r < 4; r++) o4[r] = f2h_bits(acc[mi][ni][r] + bv);
          *(uint2*)&v_o[bh * (DK * S_LEN) + (s0 >> 5) * 2048 + d * 32 + p0] =
              *(const uint2*)o4;
        } else if (t == 0) {
#pragma unroll
          for (int r = 0; r < 4; r++)
            q_o[(bh * S_LEN + s0 + r) * DK + d] =
                f2h_bits((acc[mi][ni][r] + bv) * QSCALE);
        } else {
          // K: [bh][jblk][khalf][j&31][k&31]
          size_t kb = bh * (DK * S_LEN) + (s0 >> 5) * 2048 + (d >> 5) * 1024 +
                      (s0 & 31) * 32 + (d & 31);
#pragma unroll
          for (int r = 0; r < 4; r++)
            k_o[kb + r * 32] = f2h_bits(acc[mi][ni][r] + bv);
        }
      }
    }
  }
}

// ---------------- flash attention: barrier-free, LDS-free K/V, reg dbuf ------
// Chunk = 128 j; 4 waves each own a private 32-j slice. K and V are stored by
// the QKV GEMM in fragment-native per-32-block layouts, so each MFMA operand
// is ONE fully-coalesced 64-lane b128 load (16 consecutive 64B rows) straight
// into registers. No K/V LDS, no main-loop barriers.
// ROUND-5 FIX: round 4's register double-buffer was silently serialized by the
// scheduler (VGPR_Count=116 < the ~160 needed -> loads sunk to their uses ->
// full L2 latency exposed per chunk). sched_barrier(0) fences now pin the
// issue order {compute A | load A+2 | compute B | load B+3}; with plain HIP
// loads the waitcnt pass then auto-inserts exact counted vmcnt(8) before each
// buffer's first use -- the T3/T4 counted-vmcnt pipeline, one full compute
// phase (~900 CU-cyc at 8 resident waves) between issue and use.
// PV is full-rate 16x16x32 via the lane-local k-permutation
//   pi(quad*8+e) = (e>>2)*16 + quad*4 + (e&3)
// matched by the V j-permutation done in the GEMM epilogue.
// Max-free log2-domain softmax; bias via MFMA C-operand (20 dedup'd LDS b32
// per wave-chunk); cross-wave o/l reduction via LDS at block end. XCD swizzle
// keeps each bh's K/V pinned to one XCD's L2.
__launch_bounds__(256, 2)
__global__ void attn_kernel(const unsigned short* __restrict__ Q,
                            const unsigned short* __restrict__ K,
                            const unsigned short* __restrict__ Vt,
                            const float* __restrict__ rel_bias,
                            unsigned short* __restrict__ ctx) {
  __shared__ __attribute__((aligned(16))) char smem[17664];
  float* brev = (float*)smem;              // 2112 f32 bias table (dead after loop)
  float* red  = (float*)smem;              // 64*68 f32 epilogue scratch (aliases brev)
  float* lred = (float*)(smem + 17408);    // 64 f32

  const int tid = threadIdx.x;
  const int w = tid >> 6, lane = tid & 63;
  const int col = lane & 15, quad = lane >> 4;
  const int bid = blockIdx.x;
  const int xcd = bid & 7, slot = bid >> 3;
  const int bh = (slot >> 5) * 8 + xcd;     // 8 bh per XCD (K/V set = 4MB = L2)
  const int qt = slot & 31;
  const int h = bh & (NHEADS - 1), b = bh >> 4;
  const unsigned short* qp = Q + (size_t)bh * S_LEN * DK;
  const f32x4 fzero = {0.f, 0.f, 0.f, 0.f};

  // windowed reversed bias table (log2e-scaled), idx = j - (q - qt*64) + 63
  const int tbase = 1985 - qt * 64;
#pragma unroll
  for (int it = 0; it < 9; it++) {
    int idx = it * 256 + tid;
    if (idx < 2112) {
      int rel = 3072 - (tbase + idx);
      rel = rel < 0 ? 0 : (rel > 2048 ? 2048 : rel);
      brev[idx] = rel_bias[rel * NHEADS + h] * 1.44269504089f;
    }
  }

  // Q as B-operand frags: qb[qs][ks], q = qt*64 + qs*16 + col
  f16x8 qb[4][2];
#pragma unroll
  for (int qs = 0; qs < 4; qs++)
#pragma unroll
    for (int ks = 0; ks < 2; ks++)
      qb[qs][ks] = frag_ld(qp + (size_t)(qt * 64 + qs * 16 + col) * DK + ks * 32 + quad * 8);

  f32x4 o[4][4];      // partial o[q=qs*16+quad*4+r][d=ds*16+col] over wave's 32 j
  float rsum[4];      // partial l[q=qs*16+col] over lane's j
#pragma unroll
  for (int qs = 0; qs < 4; qs++) {
#pragma unroll
    for (int ds = 0; ds < 4; ds++) o[qs][ds] = fzero;
    rsum[qs] = 0.f;
  }

  // per-lane fragment base inside a 32-block (2048 elems): row*32 + quad*8
  const int koff = col * 32 + quad * 8;
  const unsigned short* kptr = K + (size_t)bh * (DK * S_LEN) + w * 2048 + koff;
  const unsigned short* vptr = Vt + (size_t)bh * (DK * S_LEN) + w * 2048 + koff;
  // bias: idx = ck*128 + w*32 + jsub*16 + quad*4 + r - (qs*16 + col) + 63
  const float* bq = brev + (w * 32 + quad * 4 - col + 63);

  __syncthreads();  // brev ready

#define SB() __builtin_amdgcn_sched_barrier(0)

#define LOADK(dst, p)                                                          \
  dst[0][0] = frag_ld(p);                                                      \
  dst[0][1] = frag_ld(p + 1024);                                               \
  dst[1][0] = frag_ld(p + 512);                                                \
  dst[1][1] = frag_ld(p + 1536);

#define LOADV(dst, p)                                                          \
  _Pragma("unroll")                                                            \
  for (int ds = 0; ds < 4; ds++) dst[ds] = frag_ld(p + ds * 512);

#define COMPUTE(ka, vb)                                                        \
  {                                                                            \
    float bb[20];                                                              \
    _Pragma("unroll")                                                          \
    for (int g = 0; g < 5; g++)                                                \
      _Pragma("unroll")                                                        \
      for (int r = 0; r < 4; r++) bb[g * 4 + r] = bq[(g - 3) * 16 + r];        \
    _Pragma("unroll")                                                          \
    for (int qs = 0; qs < 4; qs++) {                                           \
      h16x2 pk[4];                                                             \
      _Pragma("unroll")                                                        \
      for (int js = 0; js < 2; js++) {                                         \
        f32x4 bias4;                                                           \
        _Pragma("unroll")                                                      \
        for (int r = 0; r < 4; r++) bias4[r] = bb[(js - qs + 3) * 4 + r];      \
        f32x4 sc = mfma16(ka[js][1], qb[qs][1],                                \
                          mfma16(ka[js][0], qb[qs][0], bias4));                \
        float p0 = __builtin_amdgcn_exp2f(sc[0]);                              \
        float p1 = __builtin_amdgcn_exp2f(sc[1]);                              \
        float p2 = __builtin_amdgcn_exp2f(sc[2]);                              \
        float p3 = __builtin_amdgcn_exp2f(sc[3]);                              \
        rsum[qs] += (p0 + p1) + (p2 + p3);                                     \
        pk[js * 2]     = __builtin_amdgcn_cvt_pkrtz(p0, p1);                   \
        pk[js * 2 + 1] = __builtin_amdgcn_cvt_pkrtz(p2, p3);                   \
      }                                                                        \
      f16x8 pa;                                                                \
      __builtin_memcpy(&pa, pk, 16);                                           \
      _Pragma("unroll")                                                        \
      for (int ds = 0; ds < 4; ds++)                                           \
        o[qs][ds] = mfma16(pa, vb[ds], o[qs][ds]);                             \
    }                                                                          \
  }

  f16x8 kaA[2][2], kaB[2][2], vbA[4], vbB[4];
  LOADK(kaA, kptr) LOADV(vbA, vptr) kptr += 8192; vptr += 8192;   // chunk 0
  LOADK(kaB, kptr) LOADV(vbB, vptr) kptr += 8192; vptr += 8192;   // chunk 1
  SB();
#pragma unroll 1
  for (int ck = 0; ck < 14; ck += 2) {
    COMPUTE(kaA, vbA) bq += 128;       // chunk ck       (waits vmcnt(8) auto)
    SB();
    LOADK(kaA, kptr) LOADV(vbA, vptr) kptr += 8192; vptr += 8192;  // ck+2
    SB();
    COMPUTE(kaB, vbB) bq += 128;       // chunk ck+1
    SB();
    LOADK(kaB, kptr) LOADV(vbB, vptr) kptr += 8192; vptr += 8192;  // ck+3
    SB();
  }
  COMPUTE(kaA, vbA) bq += 128;         // chunk 14
  COMPUTE(kaB, vbB)                    // chunk 15

  // finish l: sum over quads (j within wave) -> all lanes of col hold wave-partial l[q]
#pragma unroll
  for (int qs = 0; qs < 4; qs++) {
    rsum[qs] += __shfl_xor(rsum[qs], 16);
    rsum[qs] += __shfl_xor(rsum[qs], 32);
  }

  // cross-wave reduction (sequential, in-place; red stride 68 for alignment+banks)
  __syncthreads();
  for (int ws = 3; ws >= 0; ws--) {
    if (w == ws) {
#pragma unroll
      for (int qs = 0; qs < 4; qs++) {
#pragma unroll
        for (int ds = 0; ds < 4; ds++) {
#pragma unroll
          for (int r = 0; r < 4; r++) {
            int q = qs * 16 + quad * 4 + r, d = ds * 16 + col;
            if (ws == 3) red[q * 68 + d] = o[qs][ds][r];
            else         red[q * 68 + d] += o[qs][ds][r];
          }
        }
        int ql = qs * 16 + col;
        if (ws == 3) lred[ql] = rsum[qs];
        else         lred[ql] += rsum[qs];
      }
    }
    __syncthreads();
  }

  // cooperative readout: wave w handles q rows [w*16, w*16+16)
#pragma unroll
  for (int pass = 0; pass < 4; pass++) {
    int ql = w * 16 + pass * 4 + quad;
    f32x4 ov = *(const f32x4*)&red[ql * 68 + col * 4];
    float inv = 1.0f / lred[ql];
    h16x2 lo = __builtin_amdgcn_cvt_pkrtz(ov[0] * inv, ov[1] * inv);
    h16x2 hi = __builtin_amdgcn_cvt_pkrtz(ov[2] * inv, ov[3] * inv);
    uint2 pkd;
    __builtin_memcpy(&pkd.x, &lo, 4);
    __builtin_memcpy(&pkd.y, &hi, 4);
    *(uint2*)&ctx[((size_t)b * S_LEN + qt * 64 + ql) * DMODEL + h * DK + col * 4] = pkd;
  }
}

extern "C" void kernel_launch(void* const* d_in, const int* in_sizes, int n_in,
                              void* d_out, int out_size, void* d_ws, size_t ws_size,
                              hipStream_t stream) {
  (void)in_sizes; (void)n_in; (void)out_size; (void)ws_size;
  const float* x        = (const float*)d_in[0];
  const float* W_qkv    = (const float*)d_in[1];
  const float* b_qkv    = (const float*)d_in[2];
  const float* W_out    = (const float*)d_in[3];
  const float* b_out    = (const float*)d_in[4];
  const float* rel_bias = (const float*)d_in[5];
  float* out = (float*)d_out;

  char* ws = (char*)d_ws;
  unsigned short* xh     = (unsigned short*)(ws + 0);          // [8192,1024] f16 (aliases ctx)
  unsigned short* ctxh   = (unsigned short*)(ws + 0);
  unsigned short* Wqkv_t = (unsigned short*)(ws + 16777216);   // [3072,1024] f16
  unsigned short* Wout_t = (unsigned short*)(ws + 23068672);   // [1024,1024] f16
  unsigned short* Qb     = (unsigned short*)(ws + 25165824);   // [4,16,2048,64] f16
  unsigned short* Kb     = (unsigned short*)(ws + 41943040);   // [4,16,64blk,2,32,32] f16
  unsigned short* Vtb    = (unsigned short*)(ws + 58720256);   // [4,16,64blk,64,32] f16

  convert_f32_f16<<<(8192 * 1024 / 4 + 255) / 256, 256, 0, stream>>>(x, xh, 8192 * 1024 / 4);
  transpose_f32_f16<<<dim3(3072 / 32, 1024 / 32), dim3(32, 8), 0, stream>>>(W_qkv, Wqkv_t, 1024, 3072);
  transpose_f32_f16<<<dim3(1024 / 32, 1024 / 32), dim3(32, 8), 0, stream>>>(W_out, Wout_t, 1024, 1024);
  gemm_bt<<<dim3(3072 / 128, 8192 / 128), 256, 0, stream>>>(
      xh, Wqkv_t, 8192, 3072, 1024, 0, b_qkv, nullptr, Qb, Kb, Vtb);
  attn_kernel<<<4 * NHEADS * (S_LEN / 64), 256, 0, stream>>>(Qb, Kb, Vtb, rel_bias, ctxh);
  gemm_bt<<<dim3(1024 / 128, 8192 / 128), 256, 0, stream>>>(
      ctxh, Wout_t, 8192, 1024, 1024, 1, b_out, out, nullptr, nullptr, nullptr);
}